// Round 1
// baseline (1126.598 us; speedup 1.0000x reference)
//
#include <hip/hip_runtime.h>

typedef __bf16 bf16;
typedef bf16  bf16x8 __attribute__((ext_vector_type(8)));
typedef bf16  bf16x4 __attribute__((ext_vector_type(4)));
typedef float f32x4  __attribute__((ext_vector_type(4)));

#define T_SEQ 2048

// ---------------------------------------------------------------------------
// Tiled transpose fp32 [R][Cc] -> bf16 [Cc][R] (out row c, col r), batched on z.
// in  batch stride = R*Cc; out batch offset = z*Cc*ldo rows. ldo == R.
// ---------------------------------------------------------------------------
__global__ __launch_bounds__(256) void transpose_f32_bf16(
    const float* __restrict__ in, bf16* __restrict__ out, int R, int Cc, int ldo)
{
    __shared__ float tile[32][33];
    const int bx = blockIdx.x * 32;           // c
    const int by = blockIdx.y * 32;           // r
    const long bi = (long)blockIdx.z * R * Cc;
    const long bo = (long)blockIdx.z * Cc * ldo;
    const int tx = threadIdx.x, ty = threadIdx.y;
#pragma unroll
    for (int i = 0; i < 4; ++i)
        tile[ty + i * 8][tx] = in[bi + (long)(by + ty + i * 8) * Cc + bx + tx];
    __syncthreads();
#pragma unroll
    for (int i = 0; i < 4; ++i)
        out[bo + (long)(bx + ty + i * 8) * ldo + by + tx] = (bf16)tile[tx][ty + i * 8];
}

// ---------------------------------------------------------------------------
// LayerNorm: fp32 [rows][1024] -> bf16, one block (256 thr) per row.
// ---------------------------------------------------------------------------
__global__ __launch_bounds__(256) void ln_kernel(
    const float* __restrict__ x, const float* __restrict__ g,
    const float* __restrict__ bb, bf16* __restrict__ out)
{
    const long row = blockIdx.x;
    const int tid = threadIdx.x;
    const float4 v = ((const float4*)(x + row * 1024))[tid];
    float s  = v.x + v.y + v.z + v.w;
    float s2 = v.x * v.x + v.y * v.y + v.z * v.z + v.w * v.w;
#pragma unroll
    for (int off = 32; off >= 1; off >>= 1) {
        s  += __shfl_xor(s,  off, 64);
        s2 += __shfl_xor(s2, off, 64);
    }
    __shared__ float red[8];
    const int wid = tid >> 6;
    if ((tid & 63) == 0) { red[wid] = s; red[4 + wid] = s2; }
    __syncthreads();
    s  = red[0] + red[1] + red[2] + red[3];
    s2 = red[4] + red[5] + red[6] + red[7];
    const float mu   = s * (1.f / 1024.f);
    const float rstd = rsqrtf(s2 * (1.f / 1024.f) - mu * mu + 1e-5f);
    const float4 gv = ((const float4*)g)[tid];
    const float4 bv = ((const float4*)bb)[tid];
    bf16x4 ov;
    ov[0] = (bf16)((v.x - mu) * rstd * gv.x + bv.x);
    ov[1] = (bf16)((v.y - mu) * rstd * gv.y + bv.y);
    ov[2] = (bf16)((v.z - mu) * rstd * gv.z + bv.z);
    ov[3] = (bf16)((v.w - mu) * rstd * gv.w + bv.w);
    *(bf16x4*)(out + row * 1024 + tid * 4) = ov;
}

// ---------------------------------------------------------------------------
// bf16 GEMM, C[M,N] = A[M,K] * Bt[N,K]^T.  128x128 tile, BK=32, 4 waves (2x2),
// 16x16x32 MFMA, fp32 acc.  MODE: 0 = plain->bf16; 1 = bias+relu->bf16;
// 2 = bias+residual->fp32.
// ---------------------------------------------------------------------------
template <int MODE>
__global__ __launch_bounds__(256) void gemm_bt(
    const bf16* __restrict__ A, const bf16* __restrict__ Bt,
    const float* __restrict__ bias, const float* __restrict__ resid,
    void* __restrict__ outp, int M, int N, int K)
{
    __shared__ __align__(16) bf16 As[128 * 32];
    __shared__ __align__(16) bf16 Bs[128 * 32];
    const int tid = threadIdx.x;
    const int wid = tid >> 6, lane = tid & 63;
    const int wr = wid >> 1, wc = wid & 1;
    const int fr = lane & 15, fq = lane >> 4;
    const long bm = blockIdx.x, bn = blockIdx.y;

    const int srow  = tid >> 2;       // 0..63
    const int skoff = (tid & 3) * 8;  // k elem offset

    f32x4 acc[4][4];
#pragma unroll
    for (int m = 0; m < 4; ++m)
#pragma unroll
        for (int n = 0; n < 4; ++n) acc[m][n] = {0.f, 0.f, 0.f, 0.f};

    const bf16* Arow0 = A + (bm * 128 + srow) * (long)K + skoff;
    const bf16* Arow1 = Arow0 + 64 * (long)K;
    const bf16* Brow0 = Bt + (bn * 128 + srow) * (long)K + skoff;
    const bf16* Brow1 = Brow0 + 64 * (long)K;

    for (int k0 = 0; k0 < K; k0 += 32) {
        bf16x8 a0 = *(const bf16x8*)(Arow0 + k0);
        bf16x8 a1 = *(const bf16x8*)(Arow1 + k0);
        bf16x8 b0 = *(const bf16x8*)(Brow0 + k0);
        bf16x8 b1 = *(const bf16x8*)(Brow1 + k0);
        __syncthreads();
        *(bf16x8*)&As[srow * 32 + skoff]        = a0;
        *(bf16x8*)&As[(64 + srow) * 32 + skoff] = a1;
        *(bf16x8*)&Bs[srow * 32 + skoff]        = b0;
        *(bf16x8*)&Bs[(64 + srow) * 32 + skoff] = b1;
        __syncthreads();
        bf16x8 af[4], bfr[4];
#pragma unroll
        for (int m = 0; m < 4; ++m)
            af[m] = *(const bf16x8*)&As[(wr * 64 + m * 16 + fr) * 32 + fq * 8];
#pragma unroll
        for (int n = 0; n < 4; ++n)
            bfr[n] = *(const bf16x8*)&Bs[(wc * 64 + n * 16 + fr) * 32 + fq * 8];
#pragma unroll
        for (int m = 0; m < 4; ++m)
#pragma unroll
            for (int n = 0; n < 4; ++n)
                acc[m][n] = __builtin_amdgcn_mfma_f32_16x16x32_bf16(
                    af[m], bfr[n], acc[m][n], 0, 0, 0);
    }

#pragma unroll
    for (int m = 0; m < 4; ++m) {
        const long row0 = bm * 128 + wr * 64 + m * 16 + fq * 4;
#pragma unroll
        for (int n = 0; n < 4; ++n) {
            const long col = bn * 128 + wc * 64 + n * 16 + fr;
            const float bv = (MODE == 0) ? 0.f : bias[col];
#pragma unroll
            for (int j = 0; j < 4; ++j) {
                const long row = row0 + j;
                float v = acc[m][n][j] + bv;
                if (MODE == 1) v = fmaxf(v, 0.f);
                if (MODE == 2) {
                    v += resid[row * N + col];
                    ((float*)outp)[row * N + col] = v;
                } else {
                    ((bf16*)outp)[row * N + col] = (bf16)v;
                }
            }
        }
    }
}

// ---------------------------------------------------------------------------
// Flash attention, causal, scale = C^-0.5 = 1/32.
// qkv row layout per (b,t): [q(1024) | k(1024) | v(1024)], head h at h*64.
// Grid (T/64, H, B); block 256 = 4 waves; each wave owns 16 q-rows.
// Output: attn [b,t, h*64+d] bf16.
// ---------------------------------------------------------------------------
__global__ __launch_bounds__(256) void attn_kernel(
    const bf16* __restrict__ qkv, bf16* __restrict__ out)
{
    const int qblk = blockIdx.x, h = blockIdx.y, b = blockIdx.z;
    const int tid = threadIdx.x, wid = tid >> 6, lane = tid & 63;
    const int fr = lane & 15, fq = lane >> 4;
    const int q0 = qblk * 64 + wid * 16;
    const bf16* base = qkv + ((long)b * T_SEQ) * 3072 + h * 64;

    bf16x8 qf[2];
#pragma unroll
    for (int kk = 0; kk < 2; ++kk)
        qf[kk] = *(const bf16x8*)(base + (long)(q0 + fr) * 3072 + kk * 32 + fq * 8);

    f32x4 o[4];
    float mj[4], lj[4];
#pragma unroll
    for (int nd = 0; nd < 4; ++nd) o[nd] = {0.f, 0.f, 0.f, 0.f};
#pragma unroll
    for (int j = 0; j < 4; ++j) { mj[j] = -1e30f; lj[j] = 0.f; }

    __shared__ __align__(16) bf16 Vt[64][32];        // V transposed [d][token]
    __shared__ __align__(16) bf16 Plds[4][16][32];   // per-wave P

    const int nchunks = qblk * 2 + 2;
    for (int c = 0; c < nchunks; ++c) {
        const int s0 = c * 32;
        __syncthreads();
        {   // cooperative V stage, transposed
            const int tok = tid >> 3, d0 = (tid & 7) * 8;
            bf16x8 vv = *(const bf16x8*)(base + (long)(s0 + tok) * 3072 + 2048 + d0);
#pragma unroll
            for (int e = 0; e < 8; ++e) Vt[d0 + e][tok] = vv[e];
        }
        __syncthreads();

        f32x4 s[2];
        s[0] = {0.f, 0.f, 0.f, 0.f};
        s[1] = {0.f, 0.f, 0.f, 0.f};
#pragma unroll
        for (int n = 0; n < 2; ++n)
#pragma unroll
            for (int kk = 0; kk < 2; ++kk) {
                bf16x8 kf = *(const bf16x8*)(base + (long)(s0 + n * 16 + fr) * 3072
                                             + 1024 + kk * 32 + fq * 8);
                s[n] = __builtin_amdgcn_mfma_f32_16x16x32_bf16(qf[kk], kf, s[n], 0, 0, 0);
            }

        float p[2][4], corr[4];
#pragma unroll
        for (int j = 0; j < 4; ++j) {
            const int qg = q0 + fq * 4 + j;
            float v0 = s[0][j] * 0.03125f;
            float v1 = s[1][j] * 0.03125f;
            if (s0 + fr > qg)      v0 = -1e30f;
            if (s0 + 16 + fr > qg) v1 = -1e30f;
            float m = fmaxf(v0, v1);
#pragma unroll
            for (int off = 1; off <= 8; off <<= 1) m = fmaxf(m, __shfl_xor(m, off, 16));
            const float mn = fmaxf(mj[j], m);
            corr[j] = __expf(mj[j] - mn);
            mj[j] = mn;
            v0 = __expf(v0 - mn);
            v1 = __expf(v1 - mn);
            p[0][j] = v0; p[1][j] = v1;
            float r = v0 + v1;
#pragma unroll
            for (int off = 1; off <= 8; off <<= 1) r += __shfl_xor(r, off, 16);
            lj[j] = lj[j] * corr[j] + r;
        }
#pragma unroll
        for (int nd = 0; nd < 4; ++nd)
#pragma unroll
            for (int j = 0; j < 4; ++j) o[nd][j] *= corr[j];

#pragma unroll
        for (int n = 0; n < 2; ++n)
#pragma unroll
            for (int j = 0; j < 4; ++j)
                Plds[wid][fq * 4 + j][n * 16 + fr] = (bf16)p[n][j];
        asm volatile("s_waitcnt lgkmcnt(0)" ::: "memory");

        bf16x8 pf = *(const bf16x8*)&Plds[wid][fr][fq * 8];
#pragma unroll
        for (int nd = 0; nd < 4; ++nd) {
            bf16x8 vf = *(const bf16x8*)&Vt[nd * 16 + fr][fq * 8];
            o[nd] = __builtin_amdgcn_mfma_f32_16x16x32_bf16(pf, vf, o[nd], 0, 0, 0);
        }
    }

#pragma unroll
    for (int nd = 0; nd < 4; ++nd)
#pragma unroll
        for (int j = 0; j < 4; ++j) {
            const long row = (long)b * T_SEQ + q0 + fq * 4 + j;
            out[row * 1024 + h * 64 + nd * 16 + fr] = (bf16)(o[nd][j] / lj[j]);
        }
}

// ---------------------------------------------------------------------------
extern "C" void kernel_launch(void* const* d_in, const int* in_sizes, int n_in,
                              void* d_out, int out_size, void* d_ws, size_t ws_size,
                              hipStream_t stream)
{
    const float* x     = (const float*)d_in[0];
    const float* Wq    = (const float*)d_in[1];
    const float* Wk    = (const float*)d_in[2];
    const float* Wv    = (const float*)d_in[3];
    const float* Wproj = (const float*)d_in[4];
    const float* bproj = (const float*)d_in[5];
    const float* W1    = (const float*)d_in[6];
    const float* b1    = (const float*)d_in[7];
    const float* W2    = (const float*)d_in[8];
    const float* b2    = (const float*)d_in[9];
    const float* W3    = (const float*)d_in[10];
    const float* b3    = (const float*)d_in[11];
    const float* ln1g  = (const float*)d_in[12];
    const float* ln1b  = (const float*)d_in[13];
    const float* ln2g  = (const float*)d_in[14];
    const float* ln2b  = (const float*)d_in[15];

    char* ws = (char*)d_ws;
    size_t off = 0;
    auto alloc = [&](size_t bytes) {
        void* p = ws + off;
        off += (bytes + 255) & ~(size_t)255;
        return p;
    };
    bf16* Wqkv_t  = (bf16*)alloc(3072ul * 1024 * 2);
    bf16* Wproj_t = (bf16*)alloc(1024ul * 1024 * 2);
    bf16* W1_t    = (bf16*)alloc(4096ul * 1024 * 2);
    bf16* W2_t    = (bf16*)alloc(4096ul * 4096 * 2);
    bf16* W3_t    = (bf16*)alloc(1024ul * 4096 * 2);
    bf16* hbuf    = (bf16*)alloc(8192ul * 1024 * 2);
    float* x1     = (float*)alloc(8192ul * 1024 * 4);
    bf16* a1      = (bf16*)alloc(8192ul * 4096 * 2);
    char* R1      = (char*)alloc(8192ul * 4096 * 2);     // qkv+attn, later a2
    bf16* qkvb    = (bf16*)R1;
    bf16* attnb   = (bf16*)(R1 + 8192ul * 3072 * 2);
    bf16* a2      = (bf16*)R1;

    const dim3 tb(32, 8);
    // weight transposes (fp32 -> bf16, [N][K] layout)
    transpose_f32_bf16<<<dim3(2, 32, 16), tb, 0, stream>>>(Wq, Wqkv_t,                1024, 64, 1024);
    transpose_f32_bf16<<<dim3(2, 32, 16), tb, 0, stream>>>(Wk, Wqkv_t + 1024l * 1024, 1024, 64, 1024);
    transpose_f32_bf16<<<dim3(2, 32, 16), tb, 0, stream>>>(Wv, Wqkv_t + 2048l * 1024, 1024, 64, 1024);
    transpose_f32_bf16<<<dim3(32, 32, 1),   tb, 0, stream>>>(Wproj, Wproj_t, 1024, 1024, 1024);
    transpose_f32_bf16<<<dim3(128, 32, 1),  tb, 0, stream>>>(W1, W1_t, 1024, 4096, 1024);
    transpose_f32_bf16<<<dim3(128, 128, 1), tb, 0, stream>>>(W2, W2_t, 4096, 4096, 4096);
    transpose_f32_bf16<<<dim3(32, 128, 1),  tb, 0, stream>>>(W3, W3_t, 4096, 1024, 4096);

    ln_kernel<<<8192, 256, 0, stream>>>(x, ln1g, ln1b, hbuf);
    gemm_bt<0><<<dim3(64, 24), 256, 0, stream>>>(hbuf, Wqkv_t, nullptr, nullptr, qkvb, 8192, 3072, 1024);
    attn_kernel<<<dim3(32, 16, 4), 256, 0, stream>>>(qkvb, attnb);
    gemm_bt<2><<<dim3(64, 8), 256, 0, stream>>>(attnb, Wproj_t, bproj, x, x1, 8192, 1024, 1024);
    ln_kernel<<<8192, 256, 0, stream>>>(x1, ln2g, ln2b, hbuf);
    gemm_bt<1><<<dim3(64, 32), 256, 0, stream>>>(hbuf, W1_t, b1, nullptr, a1, 8192, 4096, 1024);
    gemm_bt<1><<<dim3(64, 32), 256, 0, stream>>>(a1, W2_t, b2, nullptr, a2, 8192, 4096, 4096);
    gemm_bt<2><<<dim3(64, 8), 256, 0, stream>>>(a2, W3_t, b3, x1, (float*)d_out, 8192, 1024, 4096);
}

// Round 2
// 882.547 us; speedup vs baseline: 1.2765x; 1.2765x over previous
//
#include <hip/hip_runtime.h>

typedef __bf16 bf16;
typedef bf16  bf16x8 __attribute__((ext_vector_type(8)));
typedef bf16  bf16x4 __attribute__((ext_vector_type(4)));
typedef float f32x4  __attribute__((ext_vector_type(4)));

#define T_SEQ 2048

// ---------------------------------------------------------------------------
// global -> LDS direct copy, 16B per lane. LDS dest is wave-uniform base +
// lane*16 (linear); global src is per-lane.
// ---------------------------------------------------------------------------
__device__ __forceinline__ void gload_lds16(const bf16* g, bf16* l) {
    __builtin_amdgcn_global_load_lds(
        (const __attribute__((address_space(1))) unsigned int*)g,
        (__attribute__((address_space(3))) unsigned int*)l,
        16, 0, 0);
}

// ---------------------------------------------------------------------------
// Tiled transpose fp32 [R][Cc] -> bf16 [Cc][R], batched on z.
// ---------------------------------------------------------------------------
__global__ __launch_bounds__(256) void transpose_f32_bf16(
    const float* __restrict__ in, bf16* __restrict__ out, int R, int Cc, int ldo)
{
    __shared__ float tile[32][33];
    const int bx = blockIdx.x * 32;
    const int by = blockIdx.y * 32;
    const long bi = (long)blockIdx.z * R * Cc;
    const long bo = (long)blockIdx.z * Cc * ldo;
    const int tx = threadIdx.x, ty = threadIdx.y;
#pragma unroll
    for (int i = 0; i < 4; ++i)
        tile[ty + i * 8][tx] = in[bi + (long)(by + ty + i * 8) * Cc + bx + tx];
    __syncthreads();
#pragma unroll
    for (int i = 0; i < 4; ++i)
        out[bo + (long)(bx + ty + i * 8) * ldo + by + tx] = (bf16)tile[tx][ty + i * 8];
}

// ---------------------------------------------------------------------------
// LayerNorm: fp32 [rows][1024] -> bf16, one block (256 thr) per row.
// ---------------------------------------------------------------------------
__global__ __launch_bounds__(256) void ln_kernel(
    const float* __restrict__ x, const float* __restrict__ g,
    const float* __restrict__ bb, bf16* __restrict__ out)
{
    const long row = blockIdx.x;
    const int tid = threadIdx.x;
    const float4 v = ((const float4*)(x + row * 1024))[tid];
    float s  = v.x + v.y + v.z + v.w;
    float s2 = v.x * v.x + v.y * v.y + v.z * v.z + v.w * v.w;
#pragma unroll
    for (int off = 32; off >= 1; off >>= 1) {
        s  += __shfl_xor(s,  off, 64);
        s2 += __shfl_xor(s2, off, 64);
    }
    __shared__ float red[8];
    const int wid = tid >> 6;
    if ((tid & 63) == 0) { red[wid] = s; red[4 + wid] = s2; }
    __syncthreads();
    s  = red[0] + red[1] + red[2] + red[3];
    s2 = red[4] + red[5] + red[6] + red[7];
    const float mu   = s * (1.f / 1024.f);
    const float rstd = rsqrtf(s2 * (1.f / 1024.f) - mu * mu + 1e-5f);
    const float4 gv = ((const float4*)g)[tid];
    const float4 bv = ((const float4*)bb)[tid];
    bf16x4 ov;
    ov[0] = (bf16)((v.x - mu) * rstd * gv.x + bv.x);
    ov[1] = (bf16)((v.y - mu) * rstd * gv.y + bv.y);
    ov[2] = (bf16)((v.z - mu) * rstd * gv.z + bv.z);
    ov[3] = (bf16)((v.w - mu) * rstd * gv.w + bv.w);
    *(bf16x4*)(out + row * 1024 + tid * 4) = ov;
}

// ---------------------------------------------------------------------------
// bf16 GEMM, C[M,N] = A[M,K] * Bt[N,K]^T.  128x128 tile, BK=32, 4 waves,
// 16x16x32 MFMA, global_load_lds(16B) staging (m97 structure).
// MODE: 0 plain->bf16; 1 bias+relu->bf16; 2 bias+residual->fp32.
// ---------------------------------------------------------------------------
template <int MODE>
__global__ __launch_bounds__(256) void gemm_bt(
    const bf16* __restrict__ A, const bf16* __restrict__ Bt,
    const float* __restrict__ bias, const float* __restrict__ resid,
    void* __restrict__ outp, int M, int N, int K)
{
    __shared__ __align__(16) bf16 As[128 * 32];
    __shared__ __align__(16) bf16 Bs[128 * 32];
    const int tid = threadIdx.x;
    const int wid = tid >> 6, lane = tid & 63;
    const int wr = wid >> 1, wc = wid & 1;
    const int fr = lane & 15, fq = lane >> 4;
    const long bm = blockIdx.x, bn = blockIdx.y;

    // glds staging: wave w fills chunks {2w, 2w+1} of A and of B.
    const int c0   = wid * 2;
    const int row0 = c0 * 16 + (lane >> 2);
    const int kk8  = (lane & 3) * 8;
    const bf16* gA0 = A  + ((long)(bm * 128 + row0)) * K + kk8;
    const bf16* gA1 = gA0 + 16l * K;
    const bf16* gB0 = Bt + ((long)(bn * 128 + row0)) * K + kk8;
    const bf16* gB1 = gB0 + 16l * K;
    bf16* lA0 = &As[c0 * 512];
    bf16* lA1 = &As[(c0 + 1) * 512];
    bf16* lB0 = &Bs[c0 * 512];
    bf16* lB1 = &Bs[(c0 + 1) * 512];

    f32x4 acc[4][4];
#pragma unroll
    for (int m = 0; m < 4; ++m)
#pragma unroll
        for (int n = 0; n < 4; ++n) acc[m][n] = {0.f, 0.f, 0.f, 0.f};

    for (int k0 = 0; k0 < K; k0 += 32) {
        __syncthreads();
        gload_lds16(gA0 + k0, lA0);
        gload_lds16(gA1 + k0, lA1);
        gload_lds16(gB0 + k0, lB0);
        gload_lds16(gB1 + k0, lB1);
        __syncthreads();
        bf16x8 af[4], bfr[4];
#pragma unroll
        for (int m = 0; m < 4; ++m)
            af[m] = *(const bf16x8*)&As[(wr * 64 + m * 16 + fr) * 32 + fq * 8];
#pragma unroll
        for (int n = 0; n < 4; ++n)
            bfr[n] = *(const bf16x8*)&Bs[(wc * 64 + n * 16 + fr) * 32 + fq * 8];
#pragma unroll
        for (int m = 0; m < 4; ++m)
#pragma unroll
            for (int n = 0; n < 4; ++n)
                acc[m][n] = __builtin_amdgcn_mfma_f32_16x16x32_bf16(
                    af[m], bfr[n], acc[m][n], 0, 0, 0);
    }

#pragma unroll
    for (int m = 0; m < 4; ++m) {
        const long row0o = bm * 128 + wr * 64 + m * 16 + fq * 4;
#pragma unroll
        for (int n = 0; n < 4; ++n) {
            const long col = bn * 128 + wc * 64 + n * 16 + fr;
            const float bv = (MODE == 0) ? 0.f : bias[col];
#pragma unroll
            for (int j = 0; j < 4; ++j) {
                const long row = row0o + j;
                float v = acc[m][n][j] + bv;
                if (MODE == 1) v = fmaxf(v, 0.f);
                if (MODE == 2) {
                    v += resid[row * N + col];
                    ((float*)outp)[row * N + col] = v;
                } else {
                    ((bf16*)outp)[row * N + col] = (bf16)v;
                }
            }
        }
    }
}

// ---------------------------------------------------------------------------
// Flash attention v2: causal, scale = 1/32, KVBLK=64, paired q-tiles for
// load balance. Block = 4 waves; each wave owns 16 q-rows of tile A (=pair)
// and 16 of tile B (=31-pair). K staged via global_load_lds with XOR-swizzled
// source; V reg-staged transposed with the same swizzle; P in padded LDS.
// ---------------------------------------------------------------------------
__device__ __forceinline__ void attn_step(
    const bf16* __restrict__ Ks, const bf16* __restrict__ Vt,
    bf16* __restrict__ Pp, const bf16x8* qf,
    f32x4* o, float* mj, float* lj,
    int fr, int fq, int qloc, bool diag)
{
    f32x4 s[4];
#pragma unroll
    for (int n = 0; n < 4; ++n) s[n] = {0.f, 0.f, 0.f, 0.f};
#pragma unroll
    for (int n = 0; n < 4; ++n) {
        const int t  = n * 16 + fr;
        const int sw = ((t ^ (t >> 3)) & 7) << 4;
#pragma unroll
        for (int kk = 0; kk < 2; ++kk) {
            const bf16x8 kf = *(const bf16x8*)((const char*)Ks + t * 128
                                               + ((kk * 64 + fq * 16) ^ sw));
            s[n] = __builtin_amdgcn_mfma_f32_16x16x32_bf16(qf[kk], kf, s[n], 0, 0, 0);
        }
    }
#pragma unroll
    for (int j = 0; j < 4; ++j) {
        const int qg = qloc + fq * 4 + j;
        float v0 = s[0][j] * 0.03125f, v1 = s[1][j] * 0.03125f;
        float v2 = s[2][j] * 0.03125f, v3 = s[3][j] * 0.03125f;
        if (diag) {
            if (fr      > qg) v0 = -1e30f;
            if (16 + fr > qg) v1 = -1e30f;
            if (32 + fr > qg) v2 = -1e30f;
            if (48 + fr > qg) v3 = -1e30f;
        }
        float mx = fmaxf(fmaxf(v0, v1), fmaxf(v2, v3));
#pragma unroll
        for (int off = 1; off <= 8; off <<= 1) mx = fmaxf(mx, __shfl_xor(mx, off, 16));
        const float mn   = fmaxf(mj[j], mx);
        const float corr = __expf(mj[j] - mn);
        mj[j] = mn;
        v0 = __expf(v0 - mn); v1 = __expf(v1 - mn);
        v2 = __expf(v2 - mn); v3 = __expf(v3 - mn);
        float r = v0 + v1 + v2 + v3;
#pragma unroll
        for (int off = 1; off <= 8; off <<= 1) r += __shfl_xor(r, off, 16);
        lj[j] = lj[j] * corr + r;
#pragma unroll
        for (int nd = 0; nd < 4; ++nd) o[nd][j] *= corr;
        bf16* prow = Pp + (fq * 4 + j) * 72;
        prow[fr]      = (bf16)v0;
        prow[16 + fr] = (bf16)v1;
        prow[32 + fr] = (bf16)v2;
        prow[48 + fr] = (bf16)v3;
    }
    asm volatile("s_waitcnt lgkmcnt(0)" ::: "memory");
    __builtin_amdgcn_sched_barrier(0);
    const bf16x8 pf0 = *(const bf16x8*)(Pp + fr * 72 + fq * 8);
    const bf16x8 pf1 = *(const bf16x8*)(Pp + fr * 72 + 32 + fq * 8);
#pragma unroll
    for (int nd = 0; nd < 4; ++nd) {
        const int dd = nd * 16 + fr;
        const int sw = ((dd ^ (dd >> 3)) & 7) << 4;
        const bf16x8 vf0 = *(const bf16x8*)((const char*)Vt + dd * 128 + ((fq * 16) ^ sw));
        const bf16x8 vf1 = *(const bf16x8*)((const char*)Vt + dd * 128 + ((64 + fq * 16) ^ sw));
        o[nd] = __builtin_amdgcn_mfma_f32_16x16x32_bf16(pf0, vf0, o[nd], 0, 0, 0);
        o[nd] = __builtin_amdgcn_mfma_f32_16x16x32_bf16(pf1, vf1, o[nd], 0, 0, 0);
    }
}

__global__ __launch_bounds__(256) void attn_kernel(
    const bf16* __restrict__ qkv, bf16* __restrict__ out)
{
    const int pair = blockIdx.x;          // 0..15
    const int h = blockIdx.y, b = blockIdx.z;
    const int tid = threadIdx.x, wid = tid >> 6, lane = tid & 63;
    const int fr = lane & 15, fq = lane >> 4;
    const int jA = pair, jB = 31 - pair;
    const bf16* base = qkv + ((long)b * T_SEQ) * 3072 + h * 64;

    __shared__ __align__(16) bf16 Ks[64 * 64];
    __shared__ __align__(16) bf16 Vt[64 * 64];
    __shared__ __align__(16) bf16 Plds[2][4][16 * 72];

    const int qrA = jA * 64 + wid * 16 + fr;
    const int qrB = jB * 64 + wid * 16 + fr;
    bf16x8 qfA[2], qfB[2];
#pragma unroll
    for (int kk = 0; kk < 2; ++kk) {
        qfA[kk] = *(const bf16x8*)(base + (long)qrA * 3072 + kk * 32 + fq * 8);
        qfB[kk] = *(const bf16x8*)(base + (long)qrB * 3072 + kk * 32 + fq * 8);
    }

    f32x4 oA[4], oB[4];
    float mA[4], lAv[4], mB[4], lBv[4];
#pragma unroll
    for (int nd = 0; nd < 4; ++nd) { oA[nd] = {0.f, 0.f, 0.f, 0.f}; oB[nd] = {0.f, 0.f, 0.f, 0.f}; }
#pragma unroll
    for (int j = 0; j < 4; ++j) { mA[j] = -1e30f; lAv[j] = 0.f; mB[j] = -1e30f; lBv[j] = 0.f; }

    // K glds indexing: wave w stages chunks {2w,2w+1} (8 tokens each)
    const int t_p0 = wid * 16 + (lane >> 3);
    const int t_p1 = t_p0 + 8;
    const int kcb0 = ((lane & 7) * 16) ^ (((t_p0 ^ (t_p0 >> 3)) & 7) << 4);
    const int kcb1 = ((lane & 7) * 16) ^ (((t_p1 ^ (t_p1 >> 3)) & 7) << 4);
    bf16* lK0 = &Ks[(wid * 2) * 512];
    bf16* lK1 = &Ks[(wid * 2 + 1) * 512];
    // V staging: thread covers tok=vtok and vtok+32, d = vd0..vd0+7
    const int vtok = tid >> 3;
    const int vd0  = (tid & 7) * 8;

    bf16* PA = &Plds[0][wid][0];
    bf16* PB = &Plds[1][wid][0];

    const int nch = jB + 1;
    for (int c = 0; c < nch; ++c) {
        const int s0 = c * 64;
        // issue V global loads early (registers only)
        const bf16* vsrc = base + (long)(s0 + vtok) * 3072 + 2048 + vd0;
        const bf16x8 vv0 = *(const bf16x8*)vsrc;
        const bf16x8 vv1 = *(const bf16x8*)(vsrc + 32l * 3072);
        __syncthreads();   // previous chunk's LDS reads complete
        gload_lds16(base + (long)(s0 + t_p0) * 3072 + 1024 + (kcb0 >> 1), lK0);
        gload_lds16(base + (long)(s0 + t_p1) * 3072 + 1024 + (kcb1 >> 1), lK1);
#pragma unroll
        for (int e = 0; e < 8; ++e) {
            const int d  = vd0 + e;
            const int sw = ((d ^ (d >> 3)) & 7) << 4;
            *(bf16*)((char*)Vt + ((d * 128 + vtok * 2) ^ sw))        = vv0[e];
            *(bf16*)((char*)Vt + ((d * 128 + (vtok + 32) * 2) ^ sw)) = vv1[e];
        }
        __syncthreads();   // K glds drained (vmcnt) + V writes visible
        if (c <= jA)
            attn_step(Ks, Vt, PA, qfA, oA, mA, lAv, fr, fq, wid * 16, c == jA);
        attn_step(Ks, Vt, PB, qfB, oB, mB, lBv, fr, fq, wid * 16, c == jB);
    }

#pragma unroll
    for (int nd = 0; nd < 4; ++nd)
#pragma unroll
        for (int j = 0; j < 4; ++j) {
            const long rowA = (long)b * T_SEQ + jA * 64 + wid * 16 + fq * 4 + j;
            const long rowB = (long)b * T_SEQ + jB * 64 + wid * 16 + fq * 4 + j;
            out[rowA * 1024 + h * 64 + nd * 16 + fr] = (bf16)(oA[nd][j] / lAv[j]);
            out[rowB * 1024 + h * 64 + nd * 16 + fr] = (bf16)(oB[nd][j] / lBv[j]);
        }
}

// ---------------------------------------------------------------------------
extern "C" void kernel_launch(void* const* d_in, const int* in_sizes, int n_in,
                              void* d_out, int out_size, void* d_ws, size_t ws_size,
                              hipStream_t stream)
{
    const float* x     = (const float*)d_in[0];
    const float* Wq    = (const float*)d_in[1];
    const float* Wk    = (const float*)d_in[2];
    const float* Wv    = (const float*)d_in[3];
    const float* Wproj = (const float*)d_in[4];
    const float* bproj = (const float*)d_in[5];
    const float* W1    = (const float*)d_in[6];
    const float* b1    = (const float*)d_in[7];
    const float* W2    = (const float*)d_in[8];
    const float* b2    = (const float*)d_in[9];
    const float* W3    = (const float*)d_in[10];
    const float* b3    = (const float*)d_in[11];
    const float* ln1g  = (const float*)d_in[12];
    const float* ln1b  = (const float*)d_in[13];
    const float* ln2g  = (const float*)d_in[14];
    const float* ln2b  = (const float*)d_in[15];

    char* ws = (char*)d_ws;
    size_t off = 0;
    auto alloc = [&](size_t bytes) {
        void* p = ws + off;
        off += (bytes + 255) & ~(size_t)255;
        return p;
    };
    bf16* Wqkv_t  = (bf16*)alloc(3072ul * 1024 * 2);
    bf16* Wproj_t = (bf16*)alloc(1024ul * 1024 * 2);
    bf16* W1_t    = (bf16*)alloc(4096ul * 1024 * 2);
    bf16* W2_t    = (bf16*)alloc(4096ul * 4096 * 2);
    bf16* W3_t    = (bf16*)alloc(1024ul * 4096 * 2);
    bf16* hbuf    = (bf16*)alloc(8192ul * 1024 * 2);
    float* x1     = (float*)alloc(8192ul * 1024 * 4);
    bf16* a1      = (bf16*)alloc(8192ul * 4096 * 2);
    char* R1      = (char*)alloc(8192ul * 4096 * 2);
    bf16* qkvb    = (bf16*)R1;
    bf16* attnb   = (bf16*)(R1 + 8192ul * 3072 * 2);
    bf16* a2      = (bf16*)R1;

    const dim3 tb(32, 8);
    transpose_f32_bf16<<<dim3(2, 32, 16), tb, 0, stream>>>(Wq, Wqkv_t,                1024, 64, 1024);
    transpose_f32_bf16<<<dim3(2, 32, 16), tb, 0, stream>>>(Wk, Wqkv_t + 1024l * 1024, 1024, 64, 1024);
    transpose_f32_bf16<<<dim3(2, 32, 16), tb, 0, stream>>>(Wv, Wqkv_t + 2048l * 1024, 1024, 64, 1024);
    transpose_f32_bf16<<<dim3(32, 32, 1),   tb, 0, stream>>>(Wproj, Wproj_t, 1024, 1024, 1024);
    transpose_f32_bf16<<<dim3(128, 32, 1),  tb, 0, stream>>>(W1, W1_t, 1024, 4096, 1024);
    transpose_f32_bf16<<<dim3(128, 128, 1), tb, 0, stream>>>(W2, W2_t, 4096, 4096, 4096);
    transpose_f32_bf16<<<dim3(32, 128, 1),  tb, 0, stream>>>(W3, W3_t, 4096, 1024, 4096);

    ln_kernel<<<8192, 256, 0, stream>>>(x, ln1g, ln1b, hbuf);
    gemm_bt<0><<<dim3(64, 24), 256, 0, stream>>>(hbuf, Wqkv_t, nullptr, nullptr, qkvb, 8192, 3072, 1024);
    attn_kernel<<<dim3(16, 16, 4), 256, 0, stream>>>(qkvb, attnb);
    gemm_bt<2><<<dim3(64, 8), 256, 0, stream>>>(attnb, Wproj_t, bproj, x, x1, 8192, 1024, 1024);
    ln_kernel<<<8192, 256, 0, stream>>>(x1, ln2g, ln2b, hbuf);
    gemm_bt<1><<<dim3(64, 32), 256, 0, stream>>>(hbuf, W1_t, b1, nullptr, a1, 8192, 4096, 1024);
    gemm_bt<1><<<dim3(64, 32), 256, 0, stream>>>(a1, W2_t, b2, nullptr, a2, 8192, 4096, 4096);
    gemm_bt<2><<<dim3(64, 8), 256, 0, stream>>>(a2, W3_t, b3, x1, (float*)d_out, 8192, 1024, 4096);
}

// Round 3
// 735.422 us; speedup vs baseline: 1.5319x; 1.2001x over previous
//
#include <hip/hip_runtime.h>

typedef __bf16 bf16;
typedef bf16  bf16x8 __attribute__((ext_vector_type(8)));
typedef bf16  bf16x4 __attribute__((ext_vector_type(4)));
typedef float f32x4  __attribute__((ext_vector_type(4)));

#define T_SEQ 2048

__device__ __forceinline__ void gload_lds16(const bf16* g, bf16* l) {
    __builtin_amdgcn_global_load_lds(
        (const __attribute__((address_space(1))) unsigned int*)g,
        (__attribute__((address_space(3))) unsigned int*)l,
        16, 0, 0);
}

#define VMCNT(n) asm volatile("s_waitcnt vmcnt(" #n ")" ::: "memory")
#define BAR() do { asm volatile("" ::: "memory"); __builtin_amdgcn_s_barrier(); \
                   asm volatile("" ::: "memory"); } while (0)

// ---------------------------------------------------------------------------
// Tiled transpose fp32 [R][Cc] -> bf16 [Cc][R], batched on z.
// ---------------------------------------------------------------------------
__global__ __launch_bounds__(256) void transpose_f32_bf16(
    const float* __restrict__ in, bf16* __restrict__ out, int R, int Cc, int ldo)
{
    __shared__ float tile[32][33];
    const int bx = blockIdx.x * 32;
    const int by = blockIdx.y * 32;
    const long bi = (long)blockIdx.z * R * Cc;
    const long bo = (long)blockIdx.z * Cc * ldo;
    const int tx = threadIdx.x, ty = threadIdx.y;
#pragma unroll
    for (int i = 0; i < 4; ++i)
        tile[ty + i * 8][tx] = in[bi + (long)(by + ty + i * 8) * Cc + bx + tx];
    __syncthreads();
#pragma unroll
    for (int i = 0; i < 4; ++i)
        out[bo + (long)(bx + ty + i * 8) * ldo + by + tx] = (bf16)tile[tx][ty + i * 8];
}

// ---------------------------------------------------------------------------
// LayerNorm: fp32 [rows][1024] -> bf16, one block (256 thr) per row.
// ---------------------------------------------------------------------------
__global__ __launch_bounds__(256) void ln_kernel(
    const float* __restrict__ x, const float* __restrict__ g,
    const float* __restrict__ bb, bf16* __restrict__ out)
{
    const long row = blockIdx.x;
    const int tid = threadIdx.x;
    const float4 v = ((const float4*)(x + row * 1024))[tid];
    float s  = v.x + v.y + v.z + v.w;
    float s2 = v.x * v.x + v.y * v.y + v.z * v.z + v.w * v.w;
#pragma unroll
    for (int off = 32; off >= 1; off >>= 1) {
        s  += __shfl_xor(s,  off, 64);
        s2 += __shfl_xor(s2, off, 64);
    }
    __shared__ float red[8];
    const int wid = tid >> 6;
    if ((tid & 63) == 0) { red[wid] = s; red[4 + wid] = s2; }
    __syncthreads();
    s  = red[0] + red[1] + red[2] + red[3];
    s2 = red[4] + red[5] + red[6] + red[7];
    const float mu   = s * (1.f / 1024.f);
    const float rstd = rsqrtf(s2 * (1.f / 1024.f) - mu * mu + 1e-5f);
    const float4 gv = ((const float4*)g)[tid];
    const float4 bv = ((const float4*)bb)[tid];
    bf16x4 ov;
    ov[0] = (bf16)((v.x - mu) * rstd * gv.x + bv.x);
    ov[1] = (bf16)((v.y - mu) * rstd * gv.y + bv.y);
    ov[2] = (bf16)((v.z - mu) * rstd * gv.z + bv.z);
    ov[3] = (bf16)((v.w - mu) * rstd * gv.w + bv.w);
    *(bf16x4*)(out + row * 1024 + tid * 4) = ov;
}

// ---------------------------------------------------------------------------
// 128x128 bf16 GEMM (m97 structure) — used for N=1024 outputs (proj, FF3)
// where 256^2 tiling would under-fill the GPU.
// MODE: 0 plain->bf16; 1 bias+relu->bf16; 2 bias+residual->fp32.
// ---------------------------------------------------------------------------
template <int MODE>
__global__ __launch_bounds__(256) void gemm_bt(
    const bf16* __restrict__ A, const bf16* __restrict__ Bt,
    const float* __restrict__ bias, const float* __restrict__ resid,
    void* __restrict__ outp, int M, int N, int K)
{
    __shared__ __align__(16) bf16 As[128 * 32];
    __shared__ __align__(16) bf16 Bs[128 * 32];
    const int tid = threadIdx.x;
    const int wid = tid >> 6, lane = tid & 63;
    const int wr = wid >> 1, wc = wid & 1;
    const int fr = lane & 15, fq = lane >> 4;
    const long bm = blockIdx.x, bn = blockIdx.y;

    const int c0   = wid * 2;
    const int row0 = c0 * 16 + (lane >> 2);
    const int kk8  = (lane & 3) * 8;
    const bf16* gA0 = A  + ((long)(bm * 128 + row0)) * K + kk8;
    const bf16* gA1 = gA0 + 16l * K;
    const bf16* gB0 = Bt + ((long)(bn * 128 + row0)) * K + kk8;
    const bf16* gB1 = gB0 + 16l * K;
    bf16* lA0 = &As[c0 * 512];
    bf16* lA1 = &As[(c0 + 1) * 512];
    bf16* lB0 = &Bs[c0 * 512];
    bf16* lB1 = &Bs[(c0 + 1) * 512];

    f32x4 acc[4][4];
#pragma unroll
    for (int m = 0; m < 4; ++m)
#pragma unroll
        for (int n = 0; n < 4; ++n) acc[m][n] = {0.f, 0.f, 0.f, 0.f};

    for (int k0 = 0; k0 < K; k0 += 32) {
        __syncthreads();
        gload_lds16(gA0 + k0, lA0);
        gload_lds16(gA1 + k0, lA1);
        gload_lds16(gB0 + k0, lB0);
        gload_lds16(gB1 + k0, lB1);
        __syncthreads();
        bf16x8 af[4], bfr[4];
#pragma unroll
        for (int m = 0; m < 4; ++m)
            af[m] = *(const bf16x8*)&As[(wr * 64 + m * 16 + fr) * 32 + fq * 8];
#pragma unroll
        for (int n = 0; n < 4; ++n)
            bfr[n] = *(const bf16x8*)&Bs[(wc * 64 + n * 16 + fr) * 32 + fq * 8];
#pragma unroll
        for (int m = 0; m < 4; ++m)
#pragma unroll
            for (int n = 0; n < 4; ++n)
                acc[m][n] = __builtin_amdgcn_mfma_f32_16x16x32_bf16(
                    af[m], bfr[n], acc[m][n], 0, 0, 0);
    }

#pragma unroll
    for (int m = 0; m < 4; ++m) {
        const long row0o = bm * 128 + wr * 64 + m * 16 + fq * 4;
#pragma unroll
        for (int n = 0; n < 4; ++n) {
            const long col = bn * 128 + wc * 64 + n * 16 + fr;
            const float bv = (MODE == 0) ? 0.f : bias[col];
#pragma unroll
            for (int j = 0; j < 4; ++j) {
                const long row = row0o + j;
                float v = acc[m][n][j] + bv;
                if (MODE == 1) v = fmaxf(v, 0.f);
                if (MODE == 2) {
                    v += resid[row * N + col];
                    ((float*)outp)[row * N + col] = v;
                } else {
                    ((bf16*)outp)[row * N + col] = (bf16)v;
                }
            }
        }
    }
}

// ---------------------------------------------------------------------------
// 256x256 8-phase bf16 GEMM (m201-style). BK=64, 8 waves (512 thr), 128 KiB
// LDS double-buffer, counted vmcnt (never 0 in main loop), XOR slot swizzle
// (slot ^= row&7 on 128B rows), setprio around MFMA, XCD-swizzled block id.
// Interleaved wave mapping: wave rows = wr*64 + qm*128, cols = wc*32 + qn*128,
// so each phase depends on exactly one half-tile.
// ---------------------------------------------------------------------------
#define LOADA(BUFP, QM) do {                                                   \
    const char* ab_ = (BUFP) + (size_t)((wr * 64 + (QM) * 128 + fr) * 128);    \
    _Pragma("unroll") for (int m_ = 0; m_ < 4; ++m_) {                         \
        af[m_][0] = *(const bf16x8*)(ab_ + m_ * 2048 + so0);                   \
        af[m_][1] = *(const bf16x8*)(ab_ + m_ * 2048 + so1); } } while (0)

#define LOADB(BUFP, QN) do {                                                   \
    const char* bb_ = (BUFP) + (size_t)((wc * 32 + (QN) * 128 + fr) * 128);    \
    _Pragma("unroll") for (int n_ = 0; n_ < 2; ++n_) {                         \
        bfv[n_][0] = *(const bf16x8*)(bb_ + n_ * 2048 + so0);                  \
        bfv[n_][1] = *(const bf16x8*)(bb_ + n_ * 2048 + so1); } } while (0)

#define MMA(ACC) do { __builtin_amdgcn_s_setprio(1);                           \
    _Pragma("unroll") for (int m_ = 0; m_ < 4; ++m_)                           \
    _Pragma("unroll") for (int n_ = 0; n_ < 2; ++n_) {                         \
        ACC[m_][n_] = __builtin_amdgcn_mfma_f32_16x16x32_bf16(                 \
            af[m_][0], bfv[n_][0], ACC[m_][n_], 0, 0, 0);                      \
        ACC[m_][n_] = __builtin_amdgcn_mfma_f32_16x16x32_bf16(                 \
            af[m_][1], bfv[n_][1], ACC[m_][n_], 0, 0, 0); }                    \
    __builtin_amdgcn_s_setprio(0); } while (0)

#define TILE_BODY(PRE) do {                                                    \
    const char* abuf = cAs + ((size_t)cur << 15);                              \
    const char* bbuf = cBs + ((size_t)cur << 15);                              \
    const long kn = (long)(k + 1) * 64;                                        \
    LOADA(abuf, 0);                                                            \
    LOADB(bbuf, 0);                                                            \
    if (PRE) { stageA(nxt, 0, kn); VMCNT(4); } else { VMCNT(2); }              \
    BAR(); MMA(a00); BAR();                                                    \
    LOADB(bbuf, 1);                                                            \
    if (PRE) { stageB(nxt, 0, kn); VMCNT(4); } else { VMCNT(0); }              \
    BAR(); MMA(a01); BAR();                                                    \
    LOADA(abuf, 1);                                                            \
    if (PRE) { stageB(nxt, 1, kn); }                                           \
    BAR(); MMA(a11); BAR();                                                    \
    LOADB(bbuf, 0);                                                            \
    if (PRE) { stageA(nxt, 1, kn); VMCNT(4); }                                 \
    BAR(); MMA(a10); BAR(); } while (0)

template <int MODE>
__global__ __launch_bounds__(512, 2) void gemm256(
    const bf16* __restrict__ A, const bf16* __restrict__ Bt,
    const float* __restrict__ bias, const float* __restrict__ resid,
    void* __restrict__ outp, int M, int N, int K, int nbn)
{
    extern __shared__ __align__(16) char smem[];
    char* cAs = smem;            // [2][256*64] bf16 = 2 x 32 KiB
    char* cBs = smem + 65536;    // [2][256*64] bf16

    const int tid = threadIdx.x;
    const int wid = tid >> 6, lane = tid & 63;
    const int wr = wid >> 2, wc = wid & 3;
    const int fr = lane & 15, fq = lane >> 4;

    // XCD-aware block swizzle (grid % 8 == 0 guaranteed by launcher)
    const int nwg = gridDim.x;
    const int cpx = nwg >> 3;
    const int b0  = blockIdx.x;
    const int bid = (b0 & 7) * cpx + (b0 >> 3);
    const long bm = bid / nbn, bn = bid % nbn;
    const long bmrow = bm * 256, bnrow = bn * 256;

    // staging geometry: per wave per issue, 64 lanes x 16B = 1KB linear LDS.
    const int srow0 = wid * 8 + (lane >> 3);          // row within 128-row half
    const int sslot = (lane & 7) ^ (lane >> 3);       // pre-swizzled k slot
    auto stageA = [&](int buf, int h, long kt) {
        const bf16* g = A + (size_t)(bmrow + h * 128 + srow0) * K + kt + sslot * 8;
        char* l = cAs + ((size_t)buf << 15) + h * 16384 + (size_t)wid * 1024;
        gload_lds16(g, (bf16*)l);
        gload_lds16(g + (size_t)64 * K, (bf16*)(l + 8192));
    };
    auto stageB = [&](int buf, int h, long kt) {
        const bf16* g = Bt + (size_t)(bnrow + h * 128 + srow0) * K + kt + sslot * 8;
        char* l = cBs + ((size_t)buf << 15) + h * 16384 + (size_t)wid * 1024;
        gload_lds16(g, (bf16*)l);
        gload_lds16(g + (size_t)64 * K, (bf16*)(l + 8192));
    };

    // fragment-read swizzled slot offsets
    const int sx  = fr & 7;
    const int so0 = ((fq) ^ sx) * 16;
    const int so1 = ((4 + fq) ^ sx) * 16;

    bf16x8 af[4][2], bfv[2][2];
    f32x4 a00[4][2], a01[4][2], a11[4][2], a10[4][2];
#pragma unroll
    for (int m = 0; m < 4; ++m)
#pragma unroll
        for (int n = 0; n < 2; ++n) {
            a00[m][n] = {0.f, 0.f, 0.f, 0.f}; a01[m][n] = {0.f, 0.f, 0.f, 0.f};
            a11[m][n] = {0.f, 0.f, 0.f, 0.f}; a10[m][n] = {0.f, 0.f, 0.f, 0.f};
        }

    // prologue: stage tile 0 in consumption order A0,B0,B1,A1
    stageA(0, 0, 0); stageB(0, 0, 0); stageB(0, 1, 0); stageA(0, 1, 0);
    VMCNT(4);   // A0,B0 landed; B1,A1 in flight
    BAR();

    const int NT = K >> 6;
    int cur = 0, nxt = 1;
    int k = 0;
    for (; k < NT - 1; ++k) {
        cur = k & 1; nxt = cur ^ 1;
        TILE_BODY(true);
    }
    cur = k & 1; nxt = cur ^ 1;
    TILE_BODY(false);

    // epilogue
    auto writeQ = [&](f32x4 (&acc)[4][2], int QM, int QN) {
#pragma unroll
        for (int m = 0; m < 4; ++m) {
            const long row0 = bmrow + wr * 64 + QM * 128 + m * 16 + fq * 4;
#pragma unroll
            for (int n = 0; n < 2; ++n) {
                const long col = bnrow + wc * 32 + QN * 128 + n * 16 + fr;
                const float bv = (MODE == 0) ? 0.f : bias[col];
#pragma unroll
                for (int j = 0; j < 4; ++j) {
                    const long row = row0 + j;
                    float v = acc[m][n][j] + bv;
                    if (MODE == 1) v = fmaxf(v, 0.f);
                    if (MODE == 2) {
                        v += resid[row * N + col];
                        ((float*)outp)[row * N + col] = v;
                    } else {
                        ((bf16*)outp)[row * N + col] = (bf16)v;
                    }
                }
            }
        }
    };
    writeQ(a00, 0, 0); writeQ(a01, 0, 1); writeQ(a11, 1, 1); writeQ(a10, 1, 0);
}

// ---------------------------------------------------------------------------
// Flash attention (round-2 version, unchanged): causal, scale=1/32, KVBLK=64,
// paired q-tiles, glds-staged K (swizzled source), reg-staged transposed V.
// ---------------------------------------------------------------------------
__device__ __forceinline__ void attn_step(
    const bf16* __restrict__ Ks, const bf16* __restrict__ Vt,
    bf16* __restrict__ Pp, const bf16x8* qf,
    f32x4* o, float* mj, float* lj,
    int fr, int fq, int qloc, bool diag)
{
    f32x4 s[4];
#pragma unroll
    for (int n = 0; n < 4; ++n) s[n] = {0.f, 0.f, 0.f, 0.f};
#pragma unroll
    for (int n = 0; n < 4; ++n) {
        const int t  = n * 16 + fr;
        const int sw = ((t ^ (t >> 3)) & 7) << 4;
#pragma unroll
        for (int kk = 0; kk < 2; ++kk) {
            const bf16x8 kf = *(const bf16x8*)((const char*)Ks + t * 128
                                               + ((kk * 64 + fq * 16) ^ sw));
            s[n] = __builtin_amdgcn_mfma_f32_16x16x32_bf16(qf[kk], kf, s[n], 0, 0, 0);
        }
    }
#pragma unroll
    for (int j = 0; j < 4; ++j) {
        const int qg = qloc + fq * 4 + j;
        float v0 = s[0][j] * 0.03125f, v1 = s[1][j] * 0.03125f;
        float v2 = s[2][j] * 0.03125f, v3 = s[3][j] * 0.03125f;
        if (diag) {
            if (fr      > qg) v0 = -1e30f;
            if (16 + fr > qg) v1 = -1e30f;
            if (32 + fr > qg) v2 = -1e30f;
            if (48 + fr > qg) v3 = -1e30f;
        }
        float mx = fmaxf(fmaxf(v0, v1), fmaxf(v2, v3));
#pragma unroll
        for (int off = 1; off <= 8; off <<= 1) mx = fmaxf(mx, __shfl_xor(mx, off, 16));
        const float mn   = fmaxf(mj[j], mx);
        const float corr = __expf(mj[j] - mn);
        mj[j] = mn;
        v0 = __expf(v0 - mn); v1 = __expf(v1 - mn);
        v2 = __expf(v2 - mn); v3 = __expf(v3 - mn);
        float r = v0 + v1 + v2 + v3;
#pragma unroll
        for (int off = 1; off <= 8; off <<= 1) r += __shfl_xor(r, off, 16);
        lj[j] = lj[j] * corr + r;
#pragma unroll
        for (int nd = 0; nd < 4; ++nd) o[nd][j] *= corr;
        bf16* prow = Pp + (fq * 4 + j) * 72;
        prow[fr]      = (bf16)v0;
        prow[16 + fr] = (bf16)v1;
        prow[32 + fr] = (bf16)v2;
        prow[48 + fr] = (bf16)v3;
    }
    asm volatile("s_waitcnt lgkmcnt(0)" ::: "memory");
    __builtin_amdgcn_sched_barrier(0);
    const bf16x8 pf0 = *(const bf16x8*)(Pp + fr * 72 + fq * 8);
    const bf16x8 pf1 = *(const bf16x8*)(Pp + fr * 72 + 32 + fq * 8);
#pragma unroll
    for (int nd = 0; nd < 4; ++nd) {
        const int dd = nd * 16 + fr;
        const int sw = ((dd ^ (dd >> 3)) & 7) << 4;
        const bf16x8 vf0 = *(const bf16x8*)((const char*)Vt + dd * 128 + ((fq * 16) ^ sw));
        const bf16x8 vf1 = *(const bf16x8*)((const char*)Vt + dd * 128 + ((64 + fq * 16) ^ sw));
        o[nd] = __builtin_amdgcn_mfma_f32_16x16x32_bf16(pf0, vf0, o[nd], 0, 0, 0);
        o[nd] = __builtin_amdgcn_mfma_f32_16x16x32_bf16(pf1, vf1, o[nd], 0, 0, 0);
    }
}

__global__ __launch_bounds__(256) void attn_kernel(
    const bf16* __restrict__ qkv, bf16* __restrict__ out)
{
    const int pair = blockIdx.x;
    const int h = blockIdx.y, b = blockIdx.z;
    const int tid = threadIdx.x, wid = tid >> 6, lane = tid & 63;
    const int fr = lane & 15, fq = lane >> 4;
    const int jA = pair, jB = 31 - pair;
    const bf16* base = qkv + ((long)b * T_SEQ) * 3072 + h * 64;

    __shared__ __align__(16) bf16 Ks[64 * 64];
    __shared__ __align__(16) bf16 Vt[64 * 64];
    __shared__ __align__(16) bf16 Plds[2][4][16 * 72];

    const int qrA = jA * 64 + wid * 16 + fr;
    const int qrB = jB * 64 + wid * 16 + fr;
    bf16x8 qfA[2], qfB[2];
#pragma unroll
    for (int kk = 0; kk < 2; ++kk) {
        qfA[kk] = *(const bf16x8*)(base + (long)qrA * 3072 + kk * 32 + fq * 8);
        qfB[kk] = *(const bf16x8*)(base + (long)qrB * 3072 + kk * 32 + fq * 8);
    }

    f32x4 oA[4], oB[4];
    float mA[4], lAv[4], mB[4], lBv[4];
#pragma unroll
    for (int nd = 0; nd < 4; ++nd) { oA[nd] = {0.f, 0.f, 0.f, 0.f}; oB[nd] = {0.f, 0.f, 0.f, 0.f}; }
#pragma unroll
    for (int j = 0; j < 4; ++j) { mA[j] = -1e30f; lAv[j] = 0.f; mB[j] = -1e30f; lBv[j] = 0.f; }

    const int t_p0 = wid * 16 + (lane >> 3);
    const int t_p1 = t_p0 + 8;
    const int kcb0 = ((lane & 7) * 16) ^ (((t_p0 ^ (t_p0 >> 3)) & 7) << 4);
    const int kcb1 = ((lane & 7) * 16) ^ (((t_p1 ^ (t_p1 >> 3)) & 7) << 4);
    bf16* lK0 = &Ks[(wid * 2) * 512];
    bf16* lK1 = &Ks[(wid * 2 + 1) * 512];
    const int vtok = tid >> 3;
    const int vd0  = (tid & 7) * 8;

    bf16* PA = &Plds[0][wid][0];
    bf16* PB = &Plds[1][wid][0];

    const int nch = jB + 1;
    for (int c = 0; c < nch; ++c) {
        const int s0 = c * 64;
        const bf16* vsrc = base + (long)(s0 + vtok) * 3072 + 2048 + vd0;
        const bf16x8 vv0 = *(const bf16x8*)vsrc;
        const bf16x8 vv1 = *(const bf16x8*)(vsrc + 32l * 3072);
        __syncthreads();
        gload_lds16(base + (long)(s0 + t_p0) * 3072 + 1024 + (kcb0 >> 1), lK0);
        gload_lds16(base + (long)(s0 + t_p1) * 3072 + 1024 + (kcb1 >> 1), lK1);
#pragma unroll
        for (int e = 0; e < 8; ++e) {
            const int d  = vd0 + e;
            const int sw = ((d ^ (d >> 3)) & 7) << 4;
            *(bf16*)((char*)Vt + ((d * 128 + vtok * 2) ^ sw))        = vv0[e];
            *(bf16*)((char*)Vt + ((d * 128 + (vtok + 32) * 2) ^ sw)) = vv1[e];
        }
        __syncthreads();
        if (c <= jA)
            attn_step(Ks, Vt, PA, qfA, oA, mA, lAv, fr, fq, wid * 16, c == jA);
        attn_step(Ks, Vt, PB, qfB, oB, mB, lBv, fr, fq, wid * 16, c == jB);
    }

#pragma unroll
    for (int nd = 0; nd < 4; ++nd)
#pragma unroll
        for (int j = 0; j < 4; ++j) {
            const long rowA = (long)b * T_SEQ + jA * 64 + wid * 16 + fq * 4 + j;
            const long rowB = (long)b * T_SEQ + jB * 64 + wid * 16 + fq * 4 + j;
            out[rowA * 1024 + h * 64 + nd * 16 + fr] = (bf16)(oA[nd][j] / lAv[j]);
            out[rowB * 1024 + h * 64 + nd * 16 + fr] = (bf16)(oB[nd][j] / lBv[j]);
        }
}

// ---------------------------------------------------------------------------
extern "C" void kernel_launch(void* const* d_in, const int* in_sizes, int n_in,
                              void* d_out, int out_size, void* d_ws, size_t ws_size,
                              hipStream_t stream)
{
    const float* x     = (const float*)d_in[0];
    const float* Wq    = (const float*)d_in[1];
    const float* Wk    = (const float*)d_in[2];
    const float* Wv    = (const float*)d_in[3];
    const float* Wproj = (const float*)d_in[4];
    const float* bproj = (const float*)d_in[5];
    const float* W1    = (const float*)d_in[6];
    const float* b1    = (const float*)d_in[7];
    const float* W2    = (const float*)d_in[8];
    const float* b2    = (const float*)d_in[9];
    const float* W3    = (const float*)d_in[10];
    const float* b3    = (const float*)d_in[11];
    const float* ln1g  = (const float*)d_in[12];
    const float* ln1b  = (const float*)d_in[13];
    const float* ln2g  = (const float*)d_in[14];
    const float* ln2b  = (const float*)d_in[15];

    char* ws = (char*)d_ws;
    size_t off = 0;
    auto alloc = [&](size_t bytes) {
        void* p = ws + off;
        off += (bytes + 255) & ~(size_t)255;
        return p;
    };
    bf16* Wqkv_t  = (bf16*)alloc(3072ul * 1024 * 2);
    bf16* Wproj_t = (bf16*)alloc(1024ul * 1024 * 2);
    bf16* W1_t    = (bf16*)alloc(4096ul * 1024 * 2);
    bf16* W2_t    = (bf16*)alloc(4096ul * 4096 * 2);
    bf16* W3_t    = (bf16*)alloc(1024ul * 4096 * 2);
    bf16* hbuf    = (bf16*)alloc(8192ul * 1024 * 2);
    float* x1     = (float*)alloc(8192ul * 1024 * 4);
    bf16* a1      = (bf16*)alloc(8192ul * 4096 * 2);
    char* R1      = (char*)alloc(8192ul * 4096 * 2);
    bf16* qkvb    = (bf16*)R1;
    bf16* attnb   = (bf16*)(R1 + 8192ul * 3072 * 2);
    bf16* a2      = (bf16*)R1;

    // allow 128 KiB dynamic LDS for gemm256
    hipFuncSetAttribute(reinterpret_cast<const void*>(&gemm256<0>),
                        hipFuncAttributeMaxDynamicSharedMemorySize, 131072);
    hipFuncSetAttribute(reinterpret_cast<const void*>(&gemm256<1>),
                        hipFuncAttributeMaxDynamicSharedMemorySize, 131072);

    const dim3 tb(32, 8);
    transpose_f32_bf16<<<dim3(2, 32, 16), tb, 0, stream>>>(Wq, Wqkv_t,                1024, 64, 1024);
    transpose_f32_bf16<<<dim3(2, 32, 16), tb, 0, stream>>>(Wk, Wqkv_t + 1024l * 1024, 1024, 64, 1024);
    transpose_f32_bf16<<<dim3(2, 32, 16), tb, 0, stream>>>(Wv, Wqkv_t + 2048l * 1024, 1024, 64, 1024);
    transpose_f32_bf16<<<dim3(32, 32, 1),   tb, 0, stream>>>(Wproj, Wproj_t, 1024, 1024, 1024);
    transpose_f32_bf16<<<dim3(128, 32, 1),  tb, 0, stream>>>(W1, W1_t, 1024, 4096, 1024);
    transpose_f32_bf16<<<dim3(128, 128, 1), tb, 0, stream>>>(W2, W2_t, 4096, 4096, 4096);
    transpose_f32_bf16<<<dim3(32, 128, 1),  tb, 0, stream>>>(W3, W3_t, 4096, 1024, 4096);

    ln_kernel<<<8192, 256, 0, stream>>>(x, ln1g, ln1b, hbuf);
    // QKV: M=8192, N=3072, K=1024 -> 32x12 = 384 blocks
    gemm256<0><<<384, 512, 131072, stream>>>(hbuf, Wqkv_t, nullptr, nullptr, qkvb,
                                             8192, 3072, 1024, 12);
    attn_kernel<<<dim3(16, 16, 4), 256, 0, stream>>>(qkvb, attnb);
    gemm_bt<2><<<dim3(64, 8), 256, 0, stream>>>(attnb, Wproj_t, bproj, x, x1, 8192, 1024, 1024);
    ln_kernel<<<8192, 256, 0, stream>>>(x1, ln2g, ln2b, hbuf);
    // FF1: M=8192, N=4096, K=1024 -> 32x16 = 512 blocks
    gemm256<1><<<512, 512, 131072, stream>>>(hbuf, W1_t, b1, nullptr, a1,
                                             8192, 4096, 1024, 16);
    // FF2: M=8192, N=4096, K=4096
    gemm256<1><<<512, 512, 131072, stream>>>(a1, W2_t, b2, nullptr, a2,
                                             8192, 4096, 4096, 16);
    gemm_bt<2><<<dim3(64, 8), 256, 0, stream>>>(a2, W3_t, b3, x1, (float*)d_out, 8192, 1024, 4096);
}

// Round 4
// 704.677 us; speedup vs baseline: 1.5987x; 1.0436x over previous
//
#include <hip/hip_runtime.h>

typedef __bf16 bf16;
typedef bf16  bf16x8 __attribute__((ext_vector_type(8)));
typedef bf16  bf16x4 __attribute__((ext_vector_type(4)));
typedef float f32x4  __attribute__((ext_vector_type(4)));

#define T_SEQ 2048

__device__ __forceinline__ void gload_lds16(const bf16* g, bf16* l) {
    __builtin_amdgcn_global_load_lds(
        (const __attribute__((address_space(1))) unsigned int*)g,
        (__attribute__((address_space(3))) unsigned int*)l,
        16, 0, 0);
}

#define VMCNT(n) asm volatile("s_waitcnt vmcnt(" #n ")" ::: "memory")
#define BAR() do { asm volatile("" ::: "memory"); __builtin_amdgcn_s_barrier(); \
                   asm volatile("" ::: "memory"); } while (0)

// ---------------------------------------------------------------------------
// Tiled transpose fp32 [R][Cc] -> bf16 [Cc][R], batched on z.
// ---------------------------------------------------------------------------
__global__ __launch_bounds__(256) void transpose_f32_bf16(
    const float* __restrict__ in, bf16* __restrict__ out, int R, int Cc, int ldo)
{
    __shared__ float tile[32][33];
    const int bx = blockIdx.x * 32;
    const int by = blockIdx.y * 32;
    const long bi = (long)blockIdx.z * R * Cc;
    const long bo = (long)blockIdx.z * Cc * ldo;
    const int tx = threadIdx.x, ty = threadIdx.y;
#pragma unroll
    for (int i = 0; i < 4; ++i)
        tile[ty + i * 8][tx] = in[bi + (long)(by + ty + i * 8) * Cc + bx + tx];
    __syncthreads();
#pragma unroll
    for (int i = 0; i < 4; ++i)
        out[bo + (long)(bx + ty + i * 8) * ldo + by + tx] = (bf16)tile[tx][ty + i * 8];
}

// ---------------------------------------------------------------------------
// LayerNorm: fp32 [rows][1024] -> bf16, one block (256 thr) per row.
// ---------------------------------------------------------------------------
__global__ __launch_bounds__(256) void ln_kernel(
    const float* __restrict__ x, const float* __restrict__ g,
    const float* __restrict__ bb, bf16* __restrict__ out)
{
    const long row = blockIdx.x;
    const int tid = threadIdx.x;
    const float4 v = ((const float4*)(x + row * 1024))[tid];
    float s  = v.x + v.y + v.z + v.w;
    float s2 = v.x * v.x + v.y * v.y + v.z * v.z + v.w * v.w;
#pragma unroll
    for (int off = 32; off >= 1; off >>= 1) {
        s  += __shfl_xor(s,  off, 64);
        s2 += __shfl_xor(s2, off, 64);
    }
    __shared__ float red[8];
    const int wid = tid >> 6;
    if ((tid & 63) == 0) { red[wid] = s; red[4 + wid] = s2; }
    __syncthreads();
    s  = red[0] + red[1] + red[2] + red[3];
    s2 = red[4] + red[5] + red[6] + red[7];
    const float mu   = s * (1.f / 1024.f);
    const float rstd = rsqrtf(s2 * (1.f / 1024.f) - mu * mu + 1e-5f);
    const float4 gv = ((const float4*)g)[tid];
    const float4 bv = ((const float4*)bb)[tid];
    bf16x4 ov;
    ov[0] = (bf16)((v.x - mu) * rstd * gv.x + bv.x);
    ov[1] = (bf16)((v.y - mu) * rstd * gv.y + bv.y);
    ov[2] = (bf16)((v.z - mu) * rstd * gv.z + bv.z);
    ov[3] = (bf16)((v.w - mu) * rstd * gv.w + bv.w);
    *(bf16x4*)(out + row * 1024 + tid * 4) = ov;
}

// ---------------------------------------------------------------------------
// Shared fragment-load / MFMA macros for the 256-row GEMMs.
// ---------------------------------------------------------------------------
#define LOADA(BUFP, QM) do {                                                   \
    const char* ab_ = (BUFP) + (size_t)((wr * 64 + (QM) * 128 + fr) * 128);    \
    _Pragma("unroll") for (int m_ = 0; m_ < 4; ++m_) {                         \
        af[m_][0] = *(const bf16x8*)(ab_ + m_ * 2048 + so0);                   \
        af[m_][1] = *(const bf16x8*)(ab_ + m_ * 2048 + so1); } } while (0)

#define LOADB(BUFP, QN) do {                                                   \
    const char* bb_ = (BUFP) + (size_t)((wc * 32 + (QN) * 128 + fr) * 128);    \
    _Pragma("unroll") for (int n_ = 0; n_ < 2; ++n_) {                         \
        bfv[n_][0] = *(const bf16x8*)(bb_ + n_ * 2048 + so0);                  \
        bfv[n_][1] = *(const bf16x8*)(bb_ + n_ * 2048 + so1); } } while (0)

#define MMA(ACC) do { __builtin_amdgcn_s_setprio(1);                           \
    _Pragma("unroll") for (int m_ = 0; m_ < 4; ++m_)                           \
    _Pragma("unroll") for (int n_ = 0; n_ < 2; ++n_) {                         \
        ACC[m_][n_] = __builtin_amdgcn_mfma_f32_16x16x32_bf16(                 \
            af[m_][0], bfv[n_][0], ACC[m_][n_], 0, 0, 0);                      \
        ACC[m_][n_] = __builtin_amdgcn_mfma_f32_16x16x32_bf16(                 \
            af[m_][1], bfv[n_][1], ACC[m_][n_], 0, 0, 0); }                    \
    __builtin_amdgcn_s_setprio(0); } while (0)

// ---------------------------------------------------------------------------
// 256x256 8-phase bf16 GEMM (m201-style). BK=64, 8 waves, 128 KiB LDS dbuf,
// counted vmcnt, XOR slot swizzle, setprio, XCD-swizzled block id.
// ---------------------------------------------------------------------------
#define TILE_BODY(PRE) do {                                                    \
    const char* abuf = cAs + ((size_t)cur << 15);                              \
    const char* bbuf = cBs + ((size_t)cur << 15);                              \
    const long kn = (long)(k + 1) * 64;                                        \
    LOADA(abuf, 0);                                                            \
    LOADB(bbuf, 0);                                                            \
    if (PRE) { stageA(nxt, 0, kn); VMCNT(4); } else { VMCNT(2); }              \
    BAR(); MMA(a00); BAR();                                                    \
    LOADB(bbuf, 1);                                                            \
    if (PRE) { stageB(nxt, 0, kn); VMCNT(4); } else { VMCNT(0); }              \
    BAR(); MMA(a01); BAR();                                                    \
    LOADA(abuf, 1);                                                            \
    if (PRE) { stageB(nxt, 1, kn); }                                           \
    BAR(); MMA(a11); BAR();                                                    \
    LOADB(bbuf, 0);                                                            \
    if (PRE) { stageA(nxt, 1, kn); VMCNT(4); }                                 \
    BAR(); MMA(a10); BAR(); } while (0)

template <int MODE>
__global__ __launch_bounds__(512, 2) void gemm256(
    const bf16* __restrict__ A, const bf16* __restrict__ Bt,
    const float* __restrict__ bias, const float* __restrict__ resid,
    void* __restrict__ outp, int M, int N, int K, int nbn)
{
    extern __shared__ __align__(16) char smem[];
    char* cAs = smem;
    char* cBs = smem + 65536;

    const int tid = threadIdx.x;
    const int wid = tid >> 6, lane = tid & 63;
    const int wr = wid >> 2, wc = wid & 3;
    const int fr = lane & 15, fq = lane >> 4;

    const int nwg = gridDim.x;
    const int cpx = nwg >> 3;
    const int b0  = blockIdx.x;
    const int bid = (b0 & 7) * cpx + (b0 >> 3);
    const long bm = bid / nbn, bn = bid % nbn;
    const long bmrow = bm * 256, bnrow = bn * 256;

    const int srow0 = wid * 8 + (lane >> 3);
    const int sslot = (lane & 7) ^ (lane >> 3);
    auto stageA = [&](int buf, int h, long kt) {
        const bf16* g = A + (size_t)(bmrow + h * 128 + srow0) * K + kt + sslot * 8;
        char* l = cAs + ((size_t)buf << 15) + h * 16384 + (size_t)wid * 1024;
        gload_lds16(g, (bf16*)l);
        gload_lds16(g + (size_t)64 * K, (bf16*)(l + 8192));
    };
    auto stageB = [&](int buf, int h, long kt) {
        const bf16* g = Bt + (size_t)(bnrow + h * 128 + srow0) * K + kt + sslot * 8;
        char* l = cBs + ((size_t)buf << 15) + h * 16384 + (size_t)wid * 1024;
        gload_lds16(g, (bf16*)l);
        gload_lds16(g + (size_t)64 * K, (bf16*)(l + 8192));
    };

    const int sx  = fr & 7;
    const int so0 = ((fq) ^ sx) * 16;
    const int so1 = ((4 + fq) ^ sx) * 16;

    bf16x8 af[4][2], bfv[2][2];
    f32x4 a00[4][2], a01[4][2], a11[4][2], a10[4][2];
#pragma unroll
    for (int m = 0; m < 4; ++m)
#pragma unroll
        for (int n = 0; n < 2; ++n) {
            a00[m][n] = {0.f, 0.f, 0.f, 0.f}; a01[m][n] = {0.f, 0.f, 0.f, 0.f};
            a11[m][n] = {0.f, 0.f, 0.f, 0.f}; a10[m][n] = {0.f, 0.f, 0.f, 0.f};
        }

    stageA(0, 0, 0); stageB(0, 0, 0); stageB(0, 1, 0); stageA(0, 1, 0);
    VMCNT(4);
    BAR();

    const int NT = K >> 6;
    int cur = 0, nxt = 1;
    int k = 0;
    for (; k < NT - 1; ++k) {
        cur = k & 1; nxt = cur ^ 1;
        TILE_BODY(true);
    }
    cur = k & 1; nxt = cur ^ 1;
    TILE_BODY(false);

    auto writeQ = [&](f32x4 (&acc)[4][2], int QM, int QN) {
#pragma unroll
        for (int m = 0; m < 4; ++m) {
            const long row0 = bmrow + wr * 64 + QM * 128 + m * 16 + fq * 4;
#pragma unroll
            for (int n = 0; n < 2; ++n) {
                const long col = bnrow + wc * 32 + QN * 128 + n * 16 + fr;
                const float bv = (MODE == 0) ? 0.f : bias[col];
#pragma unroll
                for (int j = 0; j < 4; ++j) {
                    const long row = row0 + j;
                    float v = acc[m][n][j] + bv;
                    if (MODE == 1) v = fmaxf(v, 0.f);
                    if (MODE == 2) {
                        v += resid[row * N + col];
                        ((float*)outp)[row * N + col] = v;
                    } else {
                        ((bf16*)outp)[row * N + col] = (bf16)v;
                    }
                }
            }
        }
    };
    writeQ(a00, 0, 0); writeQ(a01, 0, 1); writeQ(a11, 1, 1); writeQ(a10, 1, 0);
}

// ---------------------------------------------------------------------------
// 256x128 bf16 GEMM variant (same pipeline discipline), for N-narrow outputs
// (proj/FF3: exactly 256 blocks; QKV: 768 = 3 full rounds). BK=64, 8 waves
// (2Mx4N), 2 phases/K-tile (M-quadrants), 96 KiB LDS, counted vmcnt.
// 6 loads/tile; VMCNT(2) per phase keeps the next phase's data landed.
// ---------------------------------------------------------------------------
#define TILE_BODY_N(PRE, LAST) do {                                            \
    const char* abuf = cAs + ((size_t)cur << 15);                              \
    const char* bbuf = cBs + ((size_t)cur << 14);                              \
    const long kn = (long)(k + 1) * 64;                                        \
    LOADA(abuf, 0);                                                            \
    LOADB(bbuf, 0);                                                            \
    if (PRE) { stageA(nxt, 0, kn); VMCNT(2); } else { VMCNT(0); }              \
    BAR(); MMA(aq0); BAR();                                                    \
    LOADA(abuf, 1);                                                            \
    if (PRE) { stageB(nxt, kn); stageA(nxt, 1, kn); VMCNT(2); }                \
    if (!LAST) { BAR(); }                                                      \
    MMA(aq1);                                                                  \
    if (!LAST) { BAR(); } } while (0)

template <int MODE>
__global__ __launch_bounds__(512, 2) void gemm256n(
    const bf16* __restrict__ A, const bf16* __restrict__ Bt,
    const float* __restrict__ bias, const float* __restrict__ resid,
    void* __restrict__ outp, int M, int N, int K, int nbn)
{
    extern __shared__ __align__(16) char smem[];
    char* cAs = smem;            // 2 x 32 KiB
    char* cBs = smem + 65536;    // 2 x 16 KiB

    const int tid = threadIdx.x;
    const int wid = tid >> 6, lane = tid & 63;
    const int wr = wid >> 2, wc = wid & 3;   // 2 M-rows x 4 N-cols
    const int fr = lane & 15, fq = lane >> 4;

    const int nwg = gridDim.x;
    const int cpx = nwg >> 3;
    const int b0  = blockIdx.x;
    const int bid = (b0 & 7) * cpx + (b0 >> 3);
    const long bm = bid / nbn, bn = bid % nbn;
    const long bmrow = bm * 256, bnrow = bn * 128;

    const int srow0 = wid * 8 + (lane >> 3);
    const int sslot = (lane & 7) ^ (lane >> 3);
    auto stageA = [&](int buf, int h, long kt) {
        const bf16* g = A + (size_t)(bmrow + h * 128 + srow0) * K + kt + sslot * 8;
        char* l = cAs + ((size_t)buf << 15) + h * 16384 + (size_t)wid * 1024;
        gload_lds16(g, (bf16*)l);
        gload_lds16(g + (size_t)64 * K, (bf16*)(l + 8192));
    };
    auto stageB = [&](int buf, long kt) {
        const bf16* g = Bt + (size_t)(bnrow + srow0) * K + kt + sslot * 8;
        char* l = cBs + ((size_t)buf << 14) + (size_t)wid * 1024;
        gload_lds16(g, (bf16*)l);
        gload_lds16(g + (size_t)64 * K, (bf16*)(l + 8192));
    };

    const int sx  = fr & 7;
    const int so0 = ((fq) ^ sx) * 16;
    const int so1 = ((4 + fq) ^ sx) * 16;

    bf16x8 af[4][2], bfv[2][2];
    f32x4 aq0[4][2], aq1[4][2];
#pragma unroll
    for (int m = 0; m < 4; ++m)
#pragma unroll
        for (int n = 0; n < 2; ++n) {
            aq0[m][n] = {0.f, 0.f, 0.f, 0.f};
            aq1[m][n] = {0.f, 0.f, 0.f, 0.f};
        }

    stageA(0, 0, 0); stageB(0, 0); stageA(0, 1, 0);
    VMCNT(2);
    BAR();

    const int NT = K >> 6;
    int cur = 0, nxt = 1;
    int k = 0;
    for (; k < NT - 1; ++k) {
        cur = k & 1; nxt = cur ^ 1;
        TILE_BODY_N(true, false);
    }
    cur = k & 1; nxt = cur ^ 1;
    TILE_BODY_N(false, true);

    auto writeQ = [&](f32x4 (&acc)[4][2], int QM) {
#pragma unroll
        for (int m = 0; m < 4; ++m) {
            const long row0 = bmrow + wr * 64 + QM * 128 + m * 16 + fq * 4;
#pragma unroll
            for (int n = 0; n < 2; ++n) {
                const long col = bnrow + wc * 32 + n * 16 + fr;
                const float bv = (MODE == 0) ? 0.f : bias[col];
#pragma unroll
                for (int j = 0; j < 4; ++j) {
                    const long row = row0 + j;
                    float v = acc[m][n][j] + bv;
                    if (MODE == 1) v = fmaxf(v, 0.f);
                    if (MODE == 2) {
                        v += resid[row * N + col];
                        ((float*)outp)[row * N + col] = v;
                    } else {
                        ((bf16*)outp)[row * N + col] = (bf16)v;
                    }
                }
            }
        }
    };
    writeQ(aq0, 0); writeQ(aq1, 1);
}

// ---------------------------------------------------------------------------
// Flash attention v3: causal, scale=1/32, KVBLK=64, paired q-tiles.
// New: l via ones-column MFMA (no sum shfl-reduce), defer-max (THR=8).
// ---------------------------------------------------------------------------
__device__ __forceinline__ void attn_step(
    const bf16* __restrict__ Ks, const bf16* __restrict__ Vt,
    bf16* __restrict__ Pp, const bf16x8* qf,
    f32x4* o, f32x4& o_l, float* mj, const bf16x8 onesf,
    int fr, int fq, int qloc, bool diag)
{
    f32x4 s[4];
#pragma unroll
    for (int n = 0; n < 4; ++n) s[n] = {0.f, 0.f, 0.f, 0.f};
#pragma unroll
    for (int n = 0; n < 4; ++n) {
        const int t  = n * 16 + fr;
        const int sw = ((t ^ (t >> 3)) & 7) << 4;
#pragma unroll
        for (int kk = 0; kk < 2; ++kk) {
            const bf16x8 kf = *(const bf16x8*)((const char*)Ks + t * 128
                                               + ((kk * 64 + fq * 16) ^ sw));
            s[n] = __builtin_amdgcn_mfma_f32_16x16x32_bf16(qf[kk], kf, s[n], 0, 0, 0);
        }
    }
    float v[4][4], mxj[4];
#pragma unroll
    for (int j = 0; j < 4; ++j) {
        const int qg = qloc + fq * 4 + j;
        v[0][j] = s[0][j] * 0.03125f;
        v[1][j] = s[1][j] * 0.03125f;
        v[2][j] = s[2][j] * 0.03125f;
        v[3][j] = s[3][j] * 0.03125f;
        if (diag) {
            if (fr      > qg) v[0][j] = -1e30f;
            if (16 + fr > qg) v[1][j] = -1e30f;
            if (32 + fr > qg) v[2][j] = -1e30f;
            if (48 + fr > qg) v[3][j] = -1e30f;
        }
        float mx = fmaxf(fmaxf(v[0][j], v[1][j]), fmaxf(v[2][j], v[3][j]));
#pragma unroll
        for (int off = 1; off <= 8; off <<= 1) mx = fmaxf(mx, __shfl_xor(mx, off, 16));
        mxj[j] = mx;
    }
    float need = mxj[0] - mj[0];
    need = fmaxf(need, mxj[1] - mj[1]);
    need = fmaxf(need, mxj[2] - mj[2]);
    need = fmaxf(need, mxj[3] - mj[3]);
    if (__any(need > 8.f)) {   // rescale path (rare after warm-up)
#pragma unroll
        for (int j = 0; j < 4; ++j) {
            const float mn   = fmaxf(mj[j], mxj[j]);
            const float corr = __expf(mj[j] - mn);
            mj[j] = mn;
#pragma unroll
            for (int nd = 0; nd < 4; ++nd) o[nd][j] *= corr;
            o_l[j] *= corr;
        }
    }
#pragma unroll
    for (int j = 0; j < 4; ++j) {
        bf16* prow = Pp + (fq * 4 + j) * 72;
        prow[fr]      = (bf16)__expf(v[0][j] - mj[j]);
        prow[16 + fr] = (bf16)__expf(v[1][j] - mj[j]);
        prow[32 + fr] = (bf16)__expf(v[2][j] - mj[j]);
        prow[48 + fr] = (bf16)__expf(v[3][j] - mj[j]);
    }
    asm volatile("s_waitcnt lgkmcnt(0)" ::: "memory");
    __builtin_amdgcn_sched_barrier(0);
    const bf16x8 pf0 = *(const bf16x8*)(Pp + fr * 72 + fq * 8);
    const bf16x8 pf1 = *(const bf16x8*)(Pp + fr * 72 + 32 + fq * 8);
#pragma unroll
    for (int nd = 0; nd < 4; ++nd) {
        const int dd = nd * 16 + fr;
        const int sw = ((dd ^ (dd >> 3)) & 7) << 4;
        const bf16x8 vf0 = *(const bf16x8*)((const char*)Vt + dd * 128 + ((fq * 16) ^ sw));
        const bf16x8 vf1 = *(const bf16x8*)((const char*)Vt + dd * 128 + ((64 + fq * 16) ^ sw));
        o[nd] = __builtin_amdgcn_mfma_f32_16x16x32_bf16(pf0, vf0, o[nd], 0, 0, 0);
        o[nd] = __builtin_amdgcn_mfma_f32_16x16x32_bf16(pf1, vf1, o[nd], 0, 0, 0);
    }
    o_l = __builtin_amdgcn_mfma_f32_16x16x32_bf16(pf0, onesf, o_l, 0, 0, 0);
    o_l = __builtin_amdgcn_mfma_f32_16x16x32_bf16(pf1, onesf, o_l, 0, 0, 0);
}

__global__ __launch_bounds__(256) void attn_kernel(
    const bf16* __restrict__ qkv, bf16* __restrict__ out)
{
    const int pair = blockIdx.x;
    const int h = blockIdx.y, b = blockIdx.z;
    const int tid = threadIdx.x, wid = tid >> 6, lane = tid & 63;
    const int fr = lane & 15, fq = lane >> 4;
    const int jA = pair, jB = 31 - pair;
    const bf16* base = qkv + ((long)b * T_SEQ) * 3072 + h * 64;

    __shared__ __align__(16) bf16 Ks[64 * 64];
    __shared__ __align__(16) bf16 Vt[64 * 64];
    __shared__ __align__(16) bf16 Plds[2][4][16 * 72];

    const int qrA = jA * 64 + wid * 16 + fr;
    const int qrB = jB * 64 + wid * 16 + fr;
    bf16x8 qfA[2], qfB[2];
#pragma unroll
    for (int kk = 0; kk < 2; ++kk) {
        qfA[kk] = *(const bf16x8*)(base + (long)qrA * 3072 + kk * 32 + fq * 8);
        qfB[kk] = *(const bf16x8*)(base + (long)qrB * 3072 + kk * 32 + fq * 8);
    }

    bf16x8 onesf;
    {
        const bf16 ov = (fr == 0) ? (bf16)1.f : (bf16)0.f;
#pragma unroll
        for (int e = 0; e < 8; ++e) onesf[e] = ov;
    }

    f32x4 oA[4], oB[4], olA, olB;
    float mA[4], mB[4];
#pragma unroll
    for (int nd = 0; nd < 4; ++nd) { oA[nd] = {0.f, 0.f, 0.f, 0.f}; oB[nd] = {0.f, 0.f, 0.f, 0.f}; }
    olA = {0.f, 0.f, 0.f, 0.f}; olB = {0.f, 0.f, 0.f, 0.f};
#pragma unroll
    for (int j = 0; j < 4; ++j) { mA[j] = -1e30f; mB[j] = -1e30f; }

    const int t_p0 = wid * 16 + (lane >> 3);
    const int t_p1 = t_p0 + 8;
    const int kcb0 = ((lane & 7) * 16) ^ (((t_p0 ^ (t_p0 >> 3)) & 7) << 4);
    const int kcb1 = ((lane & 7) * 16) ^ (((t_p1 ^ (t_p1 >> 3)) & 7) << 4);
    bf16* lK0 = &Ks[(wid * 2) * 512];
    bf16* lK1 = &Ks[(wid * 2 + 1) * 512];
    const int vtok = tid >> 3;
    const int vd0  = (tid & 7) * 8;

    bf16* PA = &Plds[0][wid][0];
    bf16* PB = &Plds[1][wid][0];

    const int nch = jB + 1;
    for (int c = 0; c < nch; ++c) {
        const int s0 = c * 64;
        const bf16* vsrc = base + (long)(s0 + vtok) * 3072 + 2048 + vd0;
        const bf16x8 vv0 = *(const bf16x8*)vsrc;
        const bf16x8 vv1 = *(const bf16x8*)(vsrc + 32l * 3072);
        __syncthreads();
        gload_lds16(base + (long)(s0 + t_p0) * 3072 + 1024 + (kcb0 >> 1), lK0);
        gload_lds16(base + (long)(s0 + t_p1) * 3072 + 1024 + (kcb1 >> 1), lK1);
#pragma unroll
        for (int e = 0; e < 8; ++e) {
            const int d  = vd0 + e;
            const int sw = ((d ^ (d >> 3)) & 7) << 4;
            *(bf16*)((char*)Vt + ((d * 128 + vtok * 2) ^ sw))        = vv0[e];
            *(bf16*)((char*)Vt + ((d * 128 + (vtok + 32) * 2) ^ sw)) = vv1[e];
        }
        __syncthreads();
        if (c <= jA)
            attn_step(Ks, Vt, PA, qfA, oA, olA, mA, onesf, fr, fq, wid * 16, c == jA);
        attn_step(Ks, Vt, PB, qfB, oB, olB, mB, onesf, fr, fq, wid * 16, c == jB);
    }

#pragma unroll
    for (int j = 0; j < 4; ++j) {
        const float lA = __shfl(olA[j], lane & 48, 64);
        const float lB = __shfl(olB[j], lane & 48, 64);
        const float rA = 1.f / lA, rB = 1.f / lB;
        const long rowA = (long)b * T_SEQ + jA * 64 + wid * 16 + fq * 4 + j;
        const long rowB = (long)b * T_SEQ + jB * 64 + wid * 16 + fq * 4 + j;
#pragma unroll
        for (int nd = 0; nd < 4; ++nd) {
            out[rowA * 1024 + h * 64 + nd * 16 + fr] = (bf16)(oA[nd][j] * rA);
            out[rowB * 1024 + h * 64 + nd * 16 + fr] = (bf16)(oB[nd][j] * rB);
        }
    }
}

// ---------------------------------------------------------------------------
extern "C" void kernel_launch(void* const* d_in, const int* in_sizes, int n_in,
                              void* d_out, int out_size, void* d_ws, size_t ws_size,
                              hipStream_t stream)
{
    const float* x     = (const float*)d_in[0];
    const float* Wq    = (const float*)d_in[1];
    const float* Wk    = (const float*)d_in[2];
    const float* Wv    = (const float*)d_in[3];
    const float* Wproj = (const float*)d_in[4];
    const float* bproj = (const float*)d_in[5];
    const float* W1    = (const float*)d_in[6];
    const float* b1    = (const float*)d_in[7];
    const float* W2    = (const float*)d_in[8];
    const float* b2    = (const float*)d_in[9];
    const float* W3    = (const float*)d_in[10];
    const float* b3    = (const float*)d_in[11];
    const float* ln1g  = (const float*)d_in[12];
    const float* ln1b  = (const float*)d_in[13];
    const float* ln2g  = (const float*)d_in[14];
    const float* ln2b  = (const float*)d_in[15];

    char* ws = (char*)d_ws;
    size_t off = 0;
    auto alloc = [&](size_t bytes) {
        void* p = ws + off;
        off += (bytes + 255) & ~(size_t)255;
        return p;
    };
    bf16* Wqkv_t  = (bf16*)alloc(3072ul * 1024 * 2);
    bf16* Wproj_t = (bf16*)alloc(1024ul * 1024 * 2);
    bf16* W1_t    = (bf16*)alloc(4096ul * 1024 * 2);
    bf16* W2_t    = (bf16*)alloc(4096ul * 4096 * 2);
    bf16* W3_t    = (bf16*)alloc(1024ul * 4096 * 2);
    bf16* hbuf    = (bf16*)alloc(8192ul * 1024 * 2);
    float* x1     = (float*)alloc(8192ul * 1024 * 4);
    bf16* a1      = (bf16*)alloc(8192ul * 4096 * 2);
    char* R1      = (char*)alloc(8192ul * 4096 * 2);
    bf16* qkvb    = (bf16*)R1;
    bf16* attnb   = (bf16*)(R1 + 8192ul * 3072 * 2);
    bf16* a2      = (bf16*)R1;

    hipFuncSetAttribute(reinterpret_cast<const void*>(&gemm256<1>),
                        hipFuncAttributeMaxDynamicSharedMemorySize, 131072);
    hipFuncSetAttribute(reinterpret_cast<const void*>(&gemm256n<0>),
                        hipFuncAttributeMaxDynamicSharedMemorySize, 98304);
    hipFuncSetAttribute(reinterpret_cast<const void*>(&gemm256n<2>),
                        hipFuncAttributeMaxDynamicSharedMemorySize, 98304);

    const dim3 tb(32, 8);
    transpose_f32_bf16<<<dim3(2, 32, 16), tb, 0, stream>>>(Wq, Wqkv_t,                1024, 64, 1024);
    transpose_f32_bf16<<<dim3(2, 32, 16), tb, 0, stream>>>(Wk, Wqkv_t + 1024l * 1024, 1024, 64, 1024);
    transpose_f32_bf16<<<dim3(2, 32, 16), tb, 0, stream>>>(Wv, Wqkv_t + 2048l * 1024, 1024, 64, 1024);
    transpose_f32_bf16<<<dim3(32, 32, 1),   tb, 0, stream>>>(Wproj, Wproj_t, 1024, 1024, 1024);
    transpose_f32_bf16<<<dim3(128, 32, 1),  tb, 0, stream>>>(W1, W1_t, 1024, 4096, 1024);
    transpose_f32_bf16<<<dim3(128, 128, 1), tb, 0, stream>>>(W2, W2_t, 4096, 4096, 4096);
    transpose_f32_bf16<<<dim3(32, 128, 1),  tb, 0, stream>>>(W3, W3_t, 4096, 1024, 4096);

    ln_kernel<<<8192, 256, 0, stream>>>(x, ln1g, ln1b, hbuf);
    // QKV: 32 x 24 = 768 blocks (3 full occupancy rounds)
    gemm256n<0><<<768, 512, 98304, stream>>>(hbuf, Wqkv_t, nullptr, nullptr, qkvb,
                                             8192, 3072, 1024, 24);
    attn_kernel<<<dim3(16, 16, 4), 256, 0, stream>>>(qkvb, attnb);
    // proj: 32 x 8 = 256 blocks
    gemm256n<2><<<256, 512, 98304, stream>>>(attnb, Wproj_t, bproj, x, x1,
                                             8192, 1024, 1024, 8);
    ln_kernel<<<8192, 256, 0, stream>>>(x1, ln2g, ln2b, hbuf);
    // FF1: 32 x 16 = 512 blocks
    gemm256<1><<<512, 512, 131072, stream>>>(hbuf, W1_t, b1, nullptr, a1,
                                             8192, 4096, 1024, 16);
    // FF2: 512 blocks
    gemm256<1><<<512, 512, 131072, stream>>>(a1, W2_t, b2, nullptr, a2,
                                             8192, 4096, 4096, 16);
    // FF3: 32 x 8 = 256 blocks
    gemm256n<2><<<256, 512, 98304, stream>>>(a2, W3_t, b3, x1, (float*)d_out,
                                             8192, 1024, 4096, 8);
}